// Round 20
// baseline (433.442 us; speedup 1.0000x reference)
//
#include <hip/hip_runtime.h>

// y[n] = beta0 + sum_c X[n,c]*(beta[c] + Z[n,c]),  Z = X @ triu(Theta,1)
// R20 = R18 minus the A-LDS round-trip: A MFMA fragments are loaded DIRECTLY
// from f32 X into registers (16-row x 128B segments, L2-hot) and converted
// in-register to bf16 — no A ds_write/ds_read, no A lgkmcnt chain. LDS is
// B-only: 3 x 8 KB tribuf of pre-swizzled triu^T bf16 Tt via global_load_lds,
// counted vmcnt(1) steady state. Transposed MFMA D[c,n]; f32-X epilogue;
// XCD swizzle + heavy-first LPT; conv_theta inits y. 2 launches.

typedef __bf16 bf16_t;
typedef bf16_t bf16x8 __attribute__((ext_vector_type(8)));
typedef float f32x4 __attribute__((ext_vector_type(4)));
typedef unsigned short u16;
typedef u16 u16x4 __attribute__((ext_vector_type(4)));
typedef u16 u16x8 __attribute__((ext_vector_type(8)));

#define N_ROWS 65536
#define P_DIM  1024
#define BM 128
#define BN 128
#define BK 32

static __device__ __forceinline__ u16 f2bf(float f) {
  unsigned u = __builtin_bit_cast(unsigned, f);
  u += 0x7FFFu + ((u >> 16) & 1u);   // round-to-nearest-even
  return (u16)(u >> 16);
}

// global(16B/lane, per-lane src) -> LDS direct (wave-uniform dest + lane*16).
static __device__ __forceinline__ void gload16(const void* g, void* lds_base) {
  __builtin_amdgcn_global_load_lds(
      (const __attribute__((address_space(1))) unsigned char*)g,
      (__attribute__((address_space(3))) unsigned char*)lds_base, 16, 0, 0);
}

__global__ void __launch_bounds__(256)
init_y(float* __restrict__ y, const float* __restrict__ beta0) {
  int i = blockIdx.x * blockDim.x + threadIdx.x;
  if (i < N_ROWS) y[i] = beta0[0];
}

// ---- conv: Tt[c][q'] = triu-masked bf16 Theta^T quad, stored at
// q' = q ^ ((c>>1)&3) (segment-local within each 4-quad / 32-k group).
// Also initializes y = beta0 (grid covers 131072 threads >= N_ROWS).
__global__ void __launch_bounds__(128)
conv_theta(const float* __restrict__ Theta, u16* __restrict__ Tt,
           float* __restrict__ y, const float* __restrict__ beta0) {
  __shared__ float tile[32][33];
  const int tid = threadIdx.x;         // 0..127
  const int tg  = (blockIdx.y * gridDim.x + blockIdx.x) * 128 + tid;
  if (tg < N_ROWS) y[tg] = beta0[0];

  const int k0  = blockIdx.x * 32;
  const int c0  = blockIdx.y * 32;
  {
    const int tx = tid & 31;           // c within tile
    const int rb = tid >> 5;           // 0..3
    #pragma unroll
    for (int i = 0; i < 8; ++i) {
      int kl = rb * 8 + i;
      tile[kl][tx] = Theta[(size_t)(k0 + kl) * P_DIM + c0 + tx];
    }
  }
  __syncthreads();
  {
    const int cl = tid >> 2;           // 0..31
    const int qt = tid & 3;            // quad within this 32-k tile
    const int c  = c0 + cl;
    const int Q  = blockIdx.x * 4 + qt;  // global quad 0..127
    u16x8 w;
    #pragma unroll
    for (int e = 0; e < 8; ++e) {
      int k = Q * 8 + e;
      float v = tile[qt * 8 + e][cl];
      w[e] = (k < c) ? f2bf(v) : (u16)0;
    }
    const int qs = (qt ^ ((c >> 1) & 3));          // segment-local store pos
    *(u16x8*)(Tt + (size_t)c * P_DIM + (size_t)(blockIdx.x * 32 + qs * 8)) = w;
  }
}

// ---- main GEMM + fused epilogue: 128x128, 8 waves, BK=32,
// A direct global->reg (in-reg cvt), B tribuf LDS (counted vmcnt) ----
__global__ void __launch_bounds__(512)
gemm_r20(const float* __restrict__ X, const u16* __restrict__ Tt,
         const float* __restrict__ beta, float* __restrict__ y)
{
  __shared__ __align__(16) u16 L[3 * 4096];   // B only: 3 x 8 KB = 24 KB

  // XCD swizzle + heavy-first LPT: consecutive bids on one XCD share bm
  // (A/X-panel L2 reuse), bn descending (long-K first).
  const int nwg = (N_ROWS / BM) * (P_DIM / BN);    // 4096
  const int swz = (blockIdx.x & 7) * (nwg / 8) + (blockIdx.x >> 3);
  const int bn  = 7 - (swz & 7);
  const int bm  = swz >> 3;
  const int c0  = bn * BN;
  const int m0  = bm * BM;
  const int nkt = (bn + 1) * 4;        // K-steps of 32: 4..32 (always >= 2)

  const int tid  = threadIdx.x;
  const int lane = tid & 63;
  const int wid  = tid >> 6;           // 0..7
  const int wm   = wid >> 1;           // 0..3  (32-row strip)
  const int wn   = wid & 1;            // 0..1  (64-col half)
  const int l15  = lane & 15;
  const int lg   = lane >> 4;

  // ---- A direct-load geometry: frag mi -> row m0+wm*32+mi*16+l15, k lg*8 ----
  const float* xr0 = X + (size_t)(m0 + wm * 32 + l15) * P_DIM + lg * 8;
  const float* xr1 = xr0 + 16 * P_DIM;

  // ---- B staging geometry: chunk = wave; 16 rows x 32 k = 1 KB ----
  const int brow = wid * 16 + (lane >> 2);     // c row within tile
  const int bq   = (lane & 3) * 8;             // source quad offset (pre-swizzled)

  f32x4 acc[2][4];
  #pragma unroll
  for (int i = 0; i < 2; ++i)
    #pragma unroll
    for (int j = 0; j < 4; ++j)
      acc[i][j] = (f32x4)0.0f;

  f32x4 av0, av1, av2, av3;   // A prefetch regs: frag0 = av0,av1; frag1 = av2,av3

  #define LOAD_A(t_)                                                            \
    {                                                                           \
      const float* p0_ = xr0 + (t_) * BK;                                       \
      const float* p1_ = xr1 + (t_) * BK;                                       \
      av0 = ((const f32x4*)p0_)[0];                                             \
      av1 = ((const f32x4*)p0_)[1];                                             \
      av2 = ((const f32x4*)p1_)[0];                                             \
      av3 = ((const f32x4*)p1_)[1];                                             \
    }
  #define STAGE_B(bb_, t_)                                                      \
    gload16(Tt + (size_t)(c0 + brow) * P_DIM + (t_) * BK + bq,                  \
            &L[(bb_) * 4096 + wid * 512]);

  // prologue: B(0)->buf0, B(1)->buf1, A(0)->regs
  STAGE_B(0, 0)
  STAGE_B(1, 1)
  LOAD_A(0)
  asm volatile("s_waitcnt vmcnt(0)" ::: "memory");
  __builtin_amdgcn_sched_barrier(0);
  __builtin_amdgcn_s_barrier();
  __builtin_amdgcn_sched_barrier(0);

  for (int t = 0; t < nkt; ++t) {
    const int bcur = t % 3;
    const bool pre1 = (t + 1 < nkt);
    const bool pre2 = (t + 2 < nkt);

    // convert current A (loaded last iter, retired by last iter's vmcnt)
    bf16x8 af[2];
    {
      u16x8 w0, w1;
      #pragma unroll
      for (int j = 0; j < 4; ++j) {
        w0[j] = f2bf(av0[j]); w0[j + 4] = f2bf(av1[j]);
        w1[j] = f2bf(av2[j]); w1[j + 4] = f2bf(av3[j]);
      }
      af[0] = __builtin_bit_cast(bf16x8, w0);
      af[1] = __builtin_bit_cast(bf16x8, w1);
    }

    // issue next A loads (WAR on av after cvt) + B two ahead
    if (pre1) LOAD_A(t + 1)
    if (pre2) STAGE_B((t + 2) % 3, t + 2)

    // B fragment ds_reads — 2-bit quad-XOR -> ~2-way aliasing (free)
    bf16x8 bfr[4];
    #pragma unroll
    for (int ni = 0; ni < 4; ++ni) {
      const int cl = wn * 64 + ni * 16 + l15;
      u16x8 v = *(const u16x8*)&L[bcur * 4096 + cl * 32 + (lg ^ ((cl >> 1) & 3)) * 8];
      bfr[ni] = __builtin_bit_cast(bf16x8, v);
    }

    // TRANSPOSED MFMA: D[c,n], lane l15 = n (row), lg*4+r = c
    __builtin_amdgcn_s_setprio(1);
    #pragma unroll
    for (int mi = 0; mi < 2; ++mi)
      #pragma unroll
      for (int ni = 0; ni < 4; ++ni)
        acc[mi][ni] = __builtin_amdgcn_mfma_f32_16x16x32_bf16(bfr[ni], af[mi], acc[mi][ni], 0, 0, 0);
    __builtin_amdgcn_s_setprio(0);

    // counted wait: FIFO = [B(t+1) (last iter), A(t+1) x4, B(t+2)].
    // vmcnt(1) retires B(t+1)+A(t+1), leaves B(t+2) in flight.
    if (pre2) {
      asm volatile("s_waitcnt vmcnt(1)" ::: "memory");
    } else {
      asm volatile("s_waitcnt vmcnt(0)" ::: "memory");
    }
    __builtin_amdgcn_sched_barrier(0);
    __builtin_amdgcn_s_barrier();
    __builtin_amdgcn_sched_barrier(0);
  }
  #undef LOAD_A
  #undef STAGE_B

  // ---- epilogue: y_partial[row] = sum_c (Z[row,c] + beta[c]) * X[row,c] ----
  // D[c,n]: n = row = base+l15, c = c0 + wn*64 + ni*16 + lg*4 + r. X read f32.
  float ysum[2];
  ysum[0] = 0.0f; ysum[1] = 0.0f;

  #pragma unroll
  for (int mi = 0; mi < 2; ++mi) {
    const int row = m0 + wm * 32 + mi * 16 + l15;
    const float* xr = X + (size_t)row * P_DIM;
    #pragma unroll
    for (int ni = 0; ni < 4; ++ni) {
      const int cb = c0 + wn * 64 + ni * 16 + lg * 4;   // 4 consecutive cols
      f32x4 xw = *(const f32x4*)(xr + cb);
      f32x4 bv = *(const f32x4*)(beta + cb);
      #pragma unroll
      for (int r = 0; r < 4; ++r)
        ysum[mi] += (acc[mi][ni][r] + bv[r]) * xw[r];
    }
  }

  #pragma unroll
  for (int mi = 0; mi < 2; ++mi) {
    ysum[mi] += __shfl_xor(ysum[mi], 16);
    ysum[mi] += __shfl_xor(ysum[mi], 32);
  }
  if (lane < 16) {
    #pragma unroll
    for (int mi = 0; mi < 2; ++mi)
      atomicAdd(&y[m0 + wm * 32 + mi * 16 + l15], ysum[mi]);
  }
}

// ================= fallback (R1 kernel, 128x128) if ws too small =================
#define LDT 40
__global__ void __launch_bounds__(256)
fused_quad_fallback(const float* __restrict__ X, const float* __restrict__ beta,
                    const float* __restrict__ Theta, float* __restrict__ y)
{
  __shared__ __align__(16) u16 Alds[128 * LDT];
  __shared__ __align__(16) u16 Blds[128 * LDT];

  const int bid = blockIdx.x;
  const int bn  = bid & 7;
  const int bm  = bid >> 3;
  const int c0  = bn * 128;
  const int m0  = bm * 128;
  const int nkt = (bn + 1) * 4;

  const int tid  = threadIdx.x;
  const int lane = tid & 63;
  const int wid  = tid >> 6;
  const int wm   = wid >> 1;
  const int wn   = wid & 1;
  const int l15  = lane & 15;
  const int lg   = lane >> 4;

  f32x4 acc[4][4];
  #pragma unroll
  for (int i = 0; i < 4; ++i)
    #pragma unroll
    for (int j = 0; j < 4; ++j)
      acc[i][j] = (f32x4)0.0f;

  const int arow  = tid >> 1;
  const int ahalf = (tid & 1) * 16;
  const int kb4 = (tid >> 5) * 4;
  const int cb4 = (tid & 31) * 4;

  for (int kt = 0; kt < nkt; ++kt) {
    const int k0 = kt * 32;
    __syncthreads();
    {
      const f32x4* p = (const f32x4*)(X + (size_t)(m0 + arow) * P_DIM + k0 + ahalf);
      f32x4 v0 = p[0], v1 = p[1], v2 = p[2], v3 = p[3];
      u16x8 w0, w1;
      #pragma unroll
      for (int i = 0; i < 4; ++i) {
        w0[i] = f2bf(v0[i]); w0[i + 4] = f2bf(v1[i]);
        w1[i] = f2bf(v2[i]); w1[i + 4] = f2bf(v3[i]);
      }
      *(u16x8*)&Alds[arow * LDT + ahalf]     = w0;
      *(u16x8*)&Alds[arow * LDT + ahalf + 8] = w1;
    }
    {
      float e[4][4];
      #pragma unroll
      for (int i = 0; i < 4; ++i) {
        f32x4 r = *(const f32x4*)(Theta + (size_t)(k0 + kb4 + i) * P_DIM + c0 + cb4);
        #pragma unroll
        for (int j = 0; j < 4; ++j)
          e[i][j] = ((k0 + kb4 + i) < (c0 + cb4 + j)) ? r[j] : 0.0f;
      }
      #pragma unroll
      for (int j = 0; j < 4; ++j) {
        u16x4 wv;
        #pragma unroll
        for (int i = 0; i < 4; ++i) wv[i] = f2bf(e[i][j]);
        *(u16x4*)&Blds[(cb4 + j) * LDT + kb4] = wv;
      }
    }
    __syncthreads();

    bf16x8 af[4], bfr[4];
    #pragma unroll
    for (int mi = 0; mi < 4; ++mi) {
      u16x8 t = *(const u16x8*)&Alds[(wm * 64 + mi * 16 + l15) * LDT + lg * 8];
      af[mi] = __builtin_bit_cast(bf16x8, t);
    }
    #pragma unroll
    for (int ni = 0; ni < 4; ++ni) {
      u16x8 t = *(const u16x8*)&Blds[(wn * 64 + ni * 16 + l15) * LDT + lg * 8];
      bfr[ni] = __builtin_bit_cast(bf16x8, t);
    }
    #pragma unroll
    for (int mi = 0; mi < 4; ++mi)
      #pragma unroll
      for (int ni = 0; ni < 4; ++ni)
        acc[mi][ni] = __builtin_amdgcn_mfma_f32_16x16x32_bf16(af[mi], bfr[ni], acc[mi][ni], 0, 0, 0);
  }

  float ysum[4][4];
  #pragma unroll
  for (int mi = 0; mi < 4; ++mi)
    #pragma unroll
    for (int r = 0; r < 4; ++r)
      ysum[mi][r] = 0.0f;

  #pragma unroll
  for (int ni = 0; ni < 4; ++ni) {
    const int col = c0 + wn * 64 + ni * 16 + l15;
    const float bta = beta[col];
    #pragma unroll
    for (int mi = 0; mi < 4; ++mi) {
      const int rowb = m0 + wm * 64 + mi * 16 + lg * 4;
      #pragma unroll
      for (int r = 0; r < 4; ++r) {
        float xv = X[(size_t)(rowb + r) * P_DIM + col];
        ysum[mi][r] += (acc[mi][ni][r] + bta) * xv;
      }
    }
  }

  #pragma unroll
  for (int m = 1; m < 16; m <<= 1)
    #pragma unroll
    for (int mi = 0; mi < 4; ++mi)
      #pragma unroll
      for (int r = 0; r < 4; ++r)
        ysum[mi][r] += __shfl_xor(ysum[mi][r], m);

  if (l15 == 0) {
    #pragma unroll
    for (int mi = 0; mi < 4; ++mi)
      #pragma unroll
      for (int r = 0; r < 4; ++r)
        atomicAdd(&y[m0 + wm * 64 + mi * 16 + lg * 4 + r], ysum[mi][r]);
  }
}

extern "C" void kernel_launch(void* const* d_in, const int* in_sizes, int n_in,
                              void* d_out, int out_size, void* d_ws, size_t ws_size,
                              hipStream_t stream) {
  const float* X     = (const float*)d_in[0];
  const float* beta0 = (const float*)d_in[1];
  const float* beta  = (const float*)d_in[2];
  const float* Theta = (const float*)d_in[3];
  float* y = (float*)d_out;

  const size_t need = (size_t)P_DIM * P_DIM * 2;   // only Tt (2 MB)
  if (ws_size >= need) {
    u16* Tt = (u16*)d_ws;
    conv_theta<<<dim3(32, 32), 128, 0, stream>>>(Theta, Tt, y, beta0);
    gemm_r20<<<(N_ROWS / BM) * (P_DIM / BN), 512, 0, stream>>>(X, Tt, beta, y);
  } else {
    init_y<<<N_ROWS / 256, 256, 0, stream>>>(y, beta0);
    fused_quad_fallback<<<(N_ROWS / 128) * (P_DIM / 128), 256, 0, stream>>>(X, beta, Theta, y);
  }
}

// Round 21
// 159.110 us; speedup vs baseline: 2.7242x; 2.7242x over previous
//
#include <hip/hip_runtime.h>

// y[n] = beta0 + sum_c X[n,c]*(beta[c] + Z[n,c]),  Z = X @ triu(Theta,1)
// R21 = exact revert to R18/R16 (best verified: 163.0-163.5 us, reproduced).
// R20's A-direct-from-global regressed 2.7x (16 cache lines/instr, per-wave
// L2 re-fetch every iter, no LDS amortization). This config is the measured
// optimum of the session: 128x128 tile, 8 waves, BK=32; A reg-staged
// f32->bf16 (write-side 2-bit quad-XOR swizzle), B = pre-swizzled triu^T
// bf16 Tt via global_load_lds, B triple-buffered with counted vmcnt(2);
// transposed MFMA D[c,n] epilogue reading f32 X row-contiguously; XCD
// swizzle + heavy-first LPT; conv_theta inits y = beta0. 2 launches.

typedef __bf16 bf16_t;
typedef bf16_t bf16x8 __attribute__((ext_vector_type(8)));
typedef float f32x4 __attribute__((ext_vector_type(4)));
typedef unsigned short u16;
typedef u16 u16x4 __attribute__((ext_vector_type(4)));
typedef u16 u16x8 __attribute__((ext_vector_type(8)));

#define N_ROWS 65536
#define P_DIM  1024
#define BM 128
#define BN 128
#define BK 32

static __device__ __forceinline__ u16 f2bf(float f) {
  unsigned u = __builtin_bit_cast(unsigned, f);
  u += 0x7FFFu + ((u >> 16) & 1u);   // round-to-nearest-even
  return (u16)(u >> 16);
}

// global(16B/lane, per-lane src) -> LDS direct (wave-uniform dest + lane*16).
static __device__ __forceinline__ void gload16(const void* g, void* lds_base) {
  __builtin_amdgcn_global_load_lds(
      (const __attribute__((address_space(1))) unsigned char*)g,
      (__attribute__((address_space(3))) unsigned char*)lds_base, 16, 0, 0);
}

__global__ void __launch_bounds__(256)
init_y(float* __restrict__ y, const float* __restrict__ beta0) {
  int i = blockIdx.x * blockDim.x + threadIdx.x;
  if (i < N_ROWS) y[i] = beta0[0];
}

// ---- conv: Tt[c][q'] = triu-masked bf16 Theta^T quad, stored at
// q' = q ^ ((c>>1)&3) (segment-local within each 4-quad / 32-k group).
// Also initializes y = beta0 (grid covers 131072 threads >= N_ROWS).
__global__ void __launch_bounds__(128)
conv_theta(const float* __restrict__ Theta, u16* __restrict__ Tt,
           float* __restrict__ y, const float* __restrict__ beta0) {
  __shared__ float tile[32][33];
  const int tid = threadIdx.x;         // 0..127
  const int tg  = (blockIdx.y * gridDim.x + blockIdx.x) * 128 + tid;
  if (tg < N_ROWS) y[tg] = beta0[0];

  const int k0  = blockIdx.x * 32;
  const int c0  = blockIdx.y * 32;
  {
    const int tx = tid & 31;           // c within tile
    const int rb = tid >> 5;           // 0..3
    #pragma unroll
    for (int i = 0; i < 8; ++i) {
      int kl = rb * 8 + i;
      tile[kl][tx] = Theta[(size_t)(k0 + kl) * P_DIM + c0 + tx];
    }
  }
  __syncthreads();
  {
    const int cl = tid >> 2;           // 0..31
    const int qt = tid & 3;            // quad within this 32-k tile
    const int c  = c0 + cl;
    const int Q  = blockIdx.x * 4 + qt;  // global quad 0..127
    u16x8 w;
    #pragma unroll
    for (int e = 0; e < 8; ++e) {
      int k = Q * 8 + e;
      float v = tile[qt * 8 + e][cl];
      w[e] = (k < c) ? f2bf(v) : (u16)0;
    }
    const int qs = (qt ^ ((c >> 1) & 3));          // segment-local store pos
    *(u16x8*)(Tt + (size_t)c * P_DIM + (size_t)(blockIdx.x * 32 + qs * 8)) = w;
  }
}

// ---- main GEMM + fused epilogue: 128x128, 8 waves, BK=32,
// A dbuf (reg-staged), B tribuf (counted vmcnt) ----
__global__ void __launch_bounds__(512)
gemm_r21(const float* __restrict__ X, const u16* __restrict__ Tt,
         const float* __restrict__ beta, float* __restrict__ y)
{
  // A: 2 x 4096 u16 at 0 / 4096; B: 3 x 4096 u16 at 8192 + b*4096. 40 KB.
  __shared__ __align__(16) u16 L[20480];

  // XCD swizzle + heavy-first LPT: consecutive bids on one XCD share bm
  // (A-panel L2 reuse), bn descending (long-K first).
  const int nwg = (N_ROWS / BM) * (P_DIM / BN);    // 4096
  const int swz = (blockIdx.x & 7) * (nwg / 8) + (blockIdx.x >> 3);
  const int bn  = 7 - (swz & 7);
  const int bm  = swz >> 3;
  const int c0  = bn * BN;
  const int m0  = bm * BM;
  const int nkt = (bn + 1) * 4;        // K-steps of 32: 4..32 (always >= 2)

  const int tid  = threadIdx.x;
  const int lane = tid & 63;
  const int wid  = tid >> 6;           // 0..7
  const int wm   = wid >> 1;           // 0..3  (32-row strip)
  const int wn   = wid & 1;            // 0..1  (64-col half)
  const int l15  = lane & 15;
  const int lg   = lane >> 4;

  // ---- A staging geometry (reg-staged): thread -> row ar, 8-f32 group ap ----
  const int ar = tid >> 2;             // 0..127
  const int ap = tid & 3;              // quad 0..3 (8 f32 = 64 B)
  const int aq = (ap ^ ((ar >> 1) & 3)) * 8;   // swizzled LDS quad offset (u16)

  // ---- B staging geometry: chunk = wave; 16 rows x 32 k = 1 KB ----
  const int brow = wid * 16 + (lane >> 2);     // c row within tile
  const int bq   = (lane & 3) * 8;             // source quad offset (pre-swizzled)

  f32x4 acc[2][4];
  #pragma unroll
  for (int i = 0; i < 2; ++i)
    #pragma unroll
    for (int j = 0; j < 4; ++j)
      acc[i][j] = (f32x4)0.0f;

  f32x4 av0, av1;   // A staging registers (f32)

  #define STAGE_A_LOAD(t_)                                                      \
    {                                                                           \
      const float* s_ = X + (size_t)(m0 + ar) * P_DIM + (t_) * BK + ap * 8;     \
      av0 = ((const f32x4*)s_)[0];                                              \
      av1 = ((const f32x4*)s_)[1];                                              \
    }
  #define STAGE_A_WRITE(ab_)                                                    \
    {                                                                           \
      u16x8 w_;                                                                 \
      _Pragma("unroll")                                                         \
      for (int j = 0; j < 4; ++j) { w_[j] = f2bf(av0[j]); w_[j + 4] = f2bf(av1[j]); } \
      *(u16x8*)&L[(ab_) * 4096 + ar * 32 + aq] = w_;                            \
    }
  #define STAGE_B(bb_, t_)                                                      \
    gload16(Tt + (size_t)(c0 + brow) * P_DIM + (t_) * BK + bq,                  \
            &L[8192 + (bb_) * 4096 + wid * 512]);

  // prologue: B(0)->Bbuf0, B(1)->Bbuf1, A(0) regs -> write Abuf0
  STAGE_B(0, 0)
  STAGE_B(1, 1)
  STAGE_A_LOAD(0)
  asm volatile("s_waitcnt vmcnt(0)" ::: "memory");
  __builtin_amdgcn_sched_barrier(0);
  STAGE_A_WRITE(0)
  asm volatile("s_waitcnt lgkmcnt(0)" ::: "memory");
  __builtin_amdgcn_sched_barrier(0);
  __builtin_amdgcn_s_barrier();
  __builtin_amdgcn_sched_barrier(0);

  for (int t = 0; t < nkt; ++t) {
    const int acur = t & 1;
    const int bcur = t % 3;
    const bool pre1 = (t + 1 < nkt);
    const bool pre2 = (t + 2 < nkt);
    // issue next A loads FIRST (must retire at this iter's wait), then B two
    // ahead (stays in flight across the barrier -> ~1 full iter of slack).
    if (pre1) STAGE_A_LOAD(t + 1)
    if (pre2) STAGE_B((t + 2) % 3, t + 2)

    // fragment ds_reads — 2-bit quad-XOR -> ~2-way aliasing (free)
    bf16x8 af[2], bfr[4];
    #pragma unroll
    for (int mi = 0; mi < 2; ++mi) {
      const int rw = wm * 32 + mi * 16 + l15;
      u16x8 v = *(const u16x8*)&L[acur * 4096 + rw * 32 + (lg ^ ((rw >> 1) & 3)) * 8];
      af[mi] = __builtin_bit_cast(bf16x8, v);
    }
    #pragma unroll
    for (int ni = 0; ni < 4; ++ni) {
      const int cl = wn * 64 + ni * 16 + l15;
      u16x8 v = *(const u16x8*)&L[8192 + bcur * 4096 + cl * 32 + (lg ^ ((cl >> 1) & 3)) * 8];
      bfr[ni] = __builtin_bit_cast(bf16x8, v);
    }

    // TRANSPOSED MFMA: D[c,n], lane l15 = n (row), lg*4+r = c
    __builtin_amdgcn_s_setprio(1);
    #pragma unroll
    for (int mi = 0; mi < 2; ++mi)
      #pragma unroll
      for (int ni = 0; ni < 4; ++ni)
        acc[mi][ni] = __builtin_amdgcn_mfma_f32_16x16x32_bf16(bfr[ni], af[mi], acc[mi][ni], 0, 0, 0);
    __builtin_amdgcn_s_setprio(0);

    // counted wait: FIFO = [B(t+1) (last iter), av(t+1), B(t+2)].
    // vmcnt(2) retires B(t+1)+av(t+1), leaves B(t+2) in flight.
    if (pre2) {
      asm volatile("s_waitcnt vmcnt(2)" ::: "memory");
    } else {
      asm volatile("s_waitcnt vmcnt(0)" ::: "memory");
    }
    __builtin_amdgcn_sched_barrier(0);
    if (pre1) STAGE_A_WRITE((t + 1) & 1)
    asm volatile("s_waitcnt lgkmcnt(0)" ::: "memory");   // my ds_writes visible
    __builtin_amdgcn_sched_barrier(0);
    __builtin_amdgcn_s_barrier();
    __builtin_amdgcn_sched_barrier(0);
  }
  #undef STAGE_A_LOAD
  #undef STAGE_A_WRITE
  #undef STAGE_B

  // ---- epilogue: y_partial[row] = sum_c (Z[row,c] + beta[c]) * X[row,c] ----
  // D[c,n]: n = row = base+l15, c = c0 + wn*64 + ni*16 + lg*4 + r. X read f32.
  float ysum[2];
  ysum[0] = 0.0f; ysum[1] = 0.0f;

  #pragma unroll
  for (int mi = 0; mi < 2; ++mi) {
    const int row = m0 + wm * 32 + mi * 16 + l15;
    const float* xr = X + (size_t)row * P_DIM;
    #pragma unroll
    for (int ni = 0; ni < 4; ++ni) {
      const int cb = c0 + wn * 64 + ni * 16 + lg * 4;   // 4 consecutive cols
      f32x4 xw = *(const f32x4*)(xr + cb);
      f32x4 bv = *(const f32x4*)(beta + cb);
      #pragma unroll
      for (int r = 0; r < 4; ++r)
        ysum[mi] += (acc[mi][ni][r] + bv[r]) * xw[r];
    }
  }

  #pragma unroll
  for (int mi = 0; mi < 2; ++mi) {
    ysum[mi] += __shfl_xor(ysum[mi], 16);
    ysum[mi] += __shfl_xor(ysum[mi], 32);
  }
  if (lane < 16) {
    #pragma unroll
    for (int mi = 0; mi < 2; ++mi)
      atomicAdd(&y[m0 + wm * 32 + mi * 16 + l15], ysum[mi]);
  }
}

// ================= fallback (R1 kernel, 128x128) if ws too small =================
#define LDT 40
__global__ void __launch_bounds__(256)
fused_quad_fallback(const float* __restrict__ X, const float* __restrict__ beta,
                    const float* __restrict__ Theta, float* __restrict__ y)
{
  __shared__ __align__(16) u16 Alds[128 * LDT];
  __shared__ __align__(16) u16 Blds[128 * LDT];

  const int bid = blockIdx.x;
  const int bn  = bid & 7;
  const int bm  = bid >> 3;
  const int c0  = bn * 128;
  const int m0  = bm * 128;
  const int nkt = (bn + 1) * 4;

  const int tid  = threadIdx.x;
  const int lane = tid & 63;
  const int wid  = tid >> 6;
  const int wm   = wid >> 1;
  const int wn   = wid & 1;
  const int l15  = lane & 15;
  const int lg   = lane >> 4;

  f32x4 acc[4][4];
  #pragma unroll
  for (int i = 0; i < 4; ++i)
    #pragma unroll
    for (int j = 0; j < 4; ++j)
      acc[i][j] = (f32x4)0.0f;

  const int arow  = tid >> 1;
  const int ahalf = (tid & 1) * 16;
  const int kb4 = (tid >> 5) * 4;
  const int cb4 = (tid & 31) * 4;

  for (int kt = 0; kt < nkt; ++kt) {
    const int k0 = kt * 32;
    __syncthreads();
    {
      const f32x4* p = (const f32x4*)(X + (size_t)(m0 + arow) * P_DIM + k0 + ahalf);
      f32x4 v0 = p[0], v1 = p[1], v2 = p[2], v3 = p[3];
      u16x8 w0, w1;
      #pragma unroll
      for (int i = 0; i < 4; ++i) {
        w0[i] = f2bf(v0[i]); w0[i + 4] = f2bf(v1[i]);
        w1[i] = f2bf(v2[i]); w1[i + 4] = f2bf(v3[i]);
      }
      *(u16x8*)&Alds[arow * LDT + ahalf]     = w0;
      *(u16x8*)&Alds[arow * LDT + ahalf + 8] = w1;
    }
    {
      float e[4][4];
      #pragma unroll
      for (int i = 0; i < 4; ++i) {
        f32x4 r = *(const f32x4*)(Theta + (size_t)(k0 + kb4 + i) * P_DIM + c0 + cb4);
        #pragma unroll
        for (int j = 0; j < 4; ++j)
          e[i][j] = ((k0 + kb4 + i) < (c0 + cb4 + j)) ? r[j] : 0.0f;
      }
      #pragma unroll
      for (int j = 0; j < 4; ++j) {
        u16x4 wv;
        #pragma unroll
        for (int i = 0; i < 4; ++i) wv[i] = f2bf(e[i][j]);
        *(u16x4*)&Blds[(cb4 + j) * LDT + kb4] = wv;
      }
    }
    __syncthreads();

    bf16x8 af[4], bfr[4];
    #pragma unroll
    for (int mi = 0; mi < 4; ++mi) {
      u16x8 t = *(const u16x8*)&Alds[(wm * 64 + mi * 16 + l15) * LDT + lg * 8];
      af[mi] = __builtin_bit_cast(bf16x8, t);
    }
    #pragma unroll
    for (int ni = 0; ni < 4; ++ni) {
      u16x8 t = *(const u16x8*)&Blds[(wn * 64 + ni * 16 + l15) * LDT + lg * 8];
      bfr[ni] = __builtin_bit_cast(bf16x8, t);
    }
    #pragma unroll
    for (int mi = 0; mi < 4; ++mi)
      #pragma unroll
      for (int ni = 0; ni < 4; ++ni)
        acc[mi][ni] = __builtin_amdgcn_mfma_f32_16x16x32_bf16(af[mi], bfr[ni], acc[mi][ni], 0, 0, 0);
  }

  float ysum[4][4];
  #pragma unroll
  for (int mi = 0; mi < 4; ++mi)
    #pragma unroll
    for (int r = 0; r < 4; ++r)
      ysum[mi][r] = 0.0f;

  #pragma unroll
  for (int ni = 0; ni < 4; ++ni) {
    const int col = c0 + wn * 64 + ni * 16 + l15;
    const float bta = beta[col];
    #pragma unroll
    for (int mi = 0; mi < 4; ++mi) {
      const int rowb = m0 + wm * 64 + mi * 16 + lg * 4;
      #pragma unroll
      for (int r = 0; r < 4; ++r) {
        float xv = X[(size_t)(rowb + r) * P_DIM + col];
        ysum[mi][r] += (acc[mi][ni][r] + bta) * xv;
      }
    }
  }

  #pragma unroll
  for (int m = 1; m < 16; m <<= 1)
    #pragma unroll
    for (int mi = 0; mi < 4; ++mi)
      #pragma unroll
      for (int r = 0; r < 4; ++r)
        ysum[mi][r] += __shfl_xor(ysum[mi][r], m);

  if (l15 == 0) {
    #pragma unroll
    for (int mi = 0; mi < 4; ++mi)
      #pragma unroll
      for (int r = 0; r < 4; ++r)
        atomicAdd(&y[m0 + wm * 64 + mi * 16 + lg * 4 + r], ysum[mi][r]);
  }
}

extern "C" void kernel_launch(void* const* d_in, const int* in_sizes, int n_in,
                              void* d_out, int out_size, void* d_ws, size_t ws_size,
                              hipStream_t stream) {
  const float* X     = (const float*)d_in[0];
  const float* beta0 = (const float*)d_in[1];
  const float* beta  = (const float*)d_in[2];
  const float* Theta = (const float*)d_in[3];
  float* y = (float*)d_out;

  const size_t need = (size_t)P_DIM * P_DIM * 2;   // only Tt (2 MB)
  if (ws_size >= need) {
    u16* Tt = (u16*)d_ws;
    conv_theta<<<dim3(32, 32), 128, 0, stream>>>(Theta, Tt, y, beta0);
    gemm_r21<<<(N_ROWS / BM) * (P_DIM / BN), 512, 0, stream>>>(X, Tt, beta, y);
  } else {
    init_y<<<N_ROWS / 256, 256, 0, stream>>>(y, beta0);
    fused_quad_fallback<<<(N_ROWS / 128) * (P_DIM / 128), 256, 0, stream>>>(X, beta, Theta, y);
  }
}